// Round 1
// baseline (4055.479 us; speedup 1.0000x reference)
//
#include <hip/hip_runtime.h>
#include <math.h>

#define EMB 50
#define HID 50
#define G4  200   // 4*HID
#define NTAG 5
#define NEGV (-10000.0f)
#define TAG_START 3
#define TAG_STOP  4
#define T_MAX 4096

// ---------------------------------------------------------------------------
// K1: x = embed[sentence[t]];  pre_f[t][j] = b_f[j] + Wih_f[j]·x ; same for b
// pre layout: [0 .. T*200) fwd, [T*200 .. 2T*200) bwd
// ---------------------------------------------------------------------------
__global__ void k_embed_proj(const int* __restrict__ sent,
                             const float* __restrict__ embed,
                             const float* __restrict__ Wf, const float* __restrict__ bf,
                             const float* __restrict__ Wb, const float* __restrict__ bb,
                             float* __restrict__ pre, int T) {
  int t = blockIdx.x;
  int j = threadIdx.x;
  int idx = sent[t];
  const float* x = embed + (long long)idx * EMB;
  if (j < G4) {
    const float* wf = Wf + j * EMB;
    const float* wb = Wb + j * EMB;
    float af = bf[j], ab = bb[j];
#pragma unroll
    for (int k = 0; k < EMB; ++k) {
      float xk = x[k];
      af += wf[k] * xk;
      ab += wb[k] * xk;
    }
    pre[(long long)t * G4 + j] = af;
    pre[(long long)(T + t) * G4 + j] = ab;
  }
}

// ---------------------------------------------------------------------------
// K2: sequential LSTM. block 0 = forward, block 1 = backward. 256 threads.
// Thread j owns Whh row j in registers; h broadcast from LDS (float4 reads).
// hs layout: [T][100]  (fwd in cols 0..49, bwd in cols 50..99)
// ---------------------------------------------------------------------------
__global__ __launch_bounds__(256) void k_lstm(const float* __restrict__ pre,
                       const float* __restrict__ Whh_f,
                       const float* __restrict__ Whh_b,
                       const float* __restrict__ h0, const float* __restrict__ c0,
                       float* __restrict__ hs, int T) {
  int d = blockIdx.x;
  int j = threadIdx.x;
  const float* Whh  = d ? Whh_b : Whh_f;
  const float* preD = pre + (long long)d * T * G4;

  __shared__ __align__(16) float h_lds[52];
  __shared__ float act[G4];

  float w[52];
  if (j < G4) {
#pragma unroll
    for (int k = 0; k < HID; ++k) w[k] = Whh[j * HID + k];
    w[50] = 0.f; w[51] = 0.f;
  }
  float c = 0.f;
  if (j < HID) { h_lds[j] = h0[d * HID + j]; c = c0[d * HID + j]; }
  if (j == 50 || j == 51) h_lds[j] = 0.f;
  __syncthreads();

  int t0 = d ? (T - 1) : 0;
  float pre_cur = (j < G4) ? preD[(long long)t0 * G4 + j] : 0.f;

  for (int it = 0; it < T; ++it) {
    int t  = d ? (T - 1 - it) : it;
    int tn = d ? (T - 2 - it) : (it + 1);
    tn = tn < 0 ? 0 : (tn > T - 1 ? T - 1 : tn);
    float pre_next = (j < G4) ? preD[(long long)tn * G4 + j] : 0.f;

    if (j < G4) {
      float a0 = 0.f, a1 = 0.f, a2 = 0.f, a3 = 0.f;
#pragma unroll
      for (int k4 = 0; k4 < 13; ++k4) {
        float4 hv = *(const float4*)&h_lds[k4 * 4];
        a0 += w[k4 * 4 + 0] * hv.x;
        a1 += w[k4 * 4 + 1] * hv.y;
        a2 += w[k4 * 4 + 2] * hv.z;
        a3 += w[k4 * 4 + 3] * hv.w;
      }
      float z = pre_cur + ((a0 + a1) + (a2 + a3));
      // shared exp for sigmoid and tanh: e = exp(-z)
      float e   = __expf(-z);
      float sig = 1.f / (1.f + e);
      float th  = 2.f / (1.f + e * e) - 1.f;
      bool is_g = (j >= 100) && (j < 150);
      act[j] = is_g ? th : sig;
    }
    __syncthreads();
    if (j < HID) {
      float ig = act[j], fg = act[j + 50], gg = act[j + 100], og = act[j + 150];
      c = fg * c + ig * gg;
      float e2 = __expf(-2.f * c);
      float tc = 2.f / (1.f + e2) - 1.f;
      float h  = og * tc;
      h_lds[j] = h;
      hs[(long long)t * (2 * HID) + d * HID + j] = h;
    }
    __syncthreads();
    pre_cur = pre_next;
  }
}

// ---------------------------------------------------------------------------
// K3: feats[t][m] = bt[m] + Wt[m]·hs[t]   (dot over 100)
// ---------------------------------------------------------------------------
__global__ void k_feats(const float* __restrict__ hs, const float* __restrict__ Wt,
                        const float* __restrict__ bt, float* __restrict__ feats, int T) {
  int g = blockIdx.x * blockDim.x + threadIdx.x;
  if (g >= T * NTAG) return;
  int t = g / NTAG, m = g % NTAG;
  const float* h = hs + (long long)t * (2 * HID);
  const float* w = Wt + m * (2 * HID);
  float a = bt[m];
#pragma unroll
  for (int k = 0; k < 2 * HID; ++k) a += w[k] * h[k];
  feats[g] = a;
}

// ---------------------------------------------------------------------------
// K4: Viterbi. Phase 1 (wave 0): serial (max,+) fv scan, store fv history.
// Phase 2 (all): recompute backpointers in parallel, pack 5x3-bit functions.
// Phase 3: 12-level Hillis-Steele suffix composition scan in LDS.
// Phase 4: path[t] = S_t(last);  out[T] = score.
// ---------------------------------------------------------------------------
__global__ __launch_bounds__(1024) void k_viterbi(const float* __restrict__ feats,
                        const float* __restrict__ trans,
                        float* __restrict__ fvh,
                        float* __restrict__ out, int T) {
  __shared__ unsigned int bufA[T_MAX];
  __shared__ unsigned int bufB[T_MAX];
  __shared__ int s_last;
  int tid = threadIdx.x;

  if (tid < 64) {
    float tr[NTAG * NTAG];
#pragma unroll
    for (int i = 0; i < NTAG * NTAG; ++i) tr[i] = trans[i];
    float f0 = NEGV, f1 = NEGV, f2 = NEGV, f3 = 0.f, f4 = NEGV;
    float ft0 = feats[0], ft1 = feats[1], ft2 = feats[2], ft3 = feats[3], ft4 = feats[4];
    for (int t = 0; t < T; ++t) {
      if (tid == 0) {
        fvh[t * 5 + 0] = f0; fvh[t * 5 + 1] = f1; fvh[t * 5 + 2] = f2;
        fvh[t * 5 + 3] = f3; fvh[t * 5 + 4] = f4;
      }
      int tp = (t + 1 < T) ? (t + 1) : t;   // prefetch next feats
      float p0 = feats[tp * 5 + 0], p1 = feats[tp * 5 + 1], p2 = feats[tp * 5 + 2];
      float p3 = feats[tp * 5 + 3], p4 = feats[tp * 5 + 4];
      float n0 = fmaxf(fmaxf(fmaxf(f0 + tr[0],  f1 + tr[1]),  fmaxf(f2 + tr[2],  f3 + tr[3])),  f4 + tr[4])  + ft0;
      float n1 = fmaxf(fmaxf(fmaxf(f0 + tr[5],  f1 + tr[6]),  fmaxf(f2 + tr[7],  f3 + tr[8])),  f4 + tr[9])  + ft1;
      float n2 = fmaxf(fmaxf(fmaxf(f0 + tr[10], f1 + tr[11]), fmaxf(f2 + tr[12], f3 + tr[13])), f4 + tr[14]) + ft2;
      float n3 = fmaxf(fmaxf(fmaxf(f0 + tr[15], f1 + tr[16]), fmaxf(f2 + tr[17], f3 + tr[18])), f4 + tr[19]) + ft3;
      float n4 = fmaxf(fmaxf(fmaxf(f0 + tr[20], f1 + tr[21]), fmaxf(f2 + tr[22], f3 + tr[23])), f4 + tr[24]) + ft4;
      f0 = n0; f1 = n1; f2 = n2; f3 = n3; f4 = n4;
      ft0 = p0; ft1 = p1; ft2 = p2; ft3 = p3; ft4 = p4;
    }
    if (tid == 0) {
      fvh[T * 5 + 0] = f0; fvh[T * 5 + 1] = f1; fvh[T * 5 + 2] = f2;
      fvh[T * 5 + 3] = f3; fvh[T * 5 + 4] = f4;
    }
    // terminal = fv + trans[STOP][:]; first-max argmax
    float b0 = f0 + tr[TAG_STOP * 5 + 0], b1 = f1 + tr[TAG_STOP * 5 + 1];
    float b2 = f2 + tr[TAG_STOP * 5 + 2], b3 = f3 + tr[TAG_STOP * 5 + 3];
    float b4 = f4 + tr[TAG_STOP * 5 + 4];
    int last = 0; float best = b0;
    if (b1 > best) { best = b1; last = 1; }
    if (b2 > best) { best = b2; last = 2; }
    if (b3 > best) { best = b3; last = 3; }
    if (b4 > best) { best = b4; last = 4; }
    if (tid == 0) { out[T] = best; s_last = last; }
  }
  __syncthreads();

  // phase 2: bufA[t] = pack(bp_{t+1}) for t<T-1 ; bufA[T-1] = identity
  {
    float tr[NTAG * NTAG];
#pragma unroll
    for (int i = 0; i < NTAG * NTAG; ++i) tr[i] = trans[i];
    for (int t = tid; t < T; t += 1024) {
      unsigned pack;
      if (t == T - 1) {
        pack = 0u | (1u << 3) | (2u << 6) | (3u << 9) | (4u << 12);
      } else {
        const float* fv = fvh + (long long)(t + 1) * 5;
        float g0 = fv[0], g1 = fv[1], g2 = fv[2], g3 = fv[3], g4 = fv[4];
        pack = 0u;
#pragma unroll
        for (int nx = 0; nx < NTAG; ++nx) {
          float v0 = g0 + tr[nx * 5 + 0], v1 = g1 + tr[nx * 5 + 1], v2 = g2 + tr[nx * 5 + 2];
          float v3 = g3 + tr[nx * 5 + 3], v4 = g4 + tr[nx * 5 + 4];
          int bi = 0; float bv = v0;
          if (v1 > bv) { bv = v1; bi = 1; }
          if (v2 > bv) { bv = v2; bi = 2; }
          if (v3 > bv) { bv = v3; bi = 3; }
          if (v4 > bv) { bv = v4; bi = 4; }
          pack |= (unsigned)bi << (3 * nx);
        }
      }
      bufA[t] = pack;
    }
  }
  __syncthreads();

  // phase 3: suffix composition scan: A[t] <- A[t] ∘ A[t+d]  (A[t] applied last)
  unsigned int* cur = bufA;
  unsigned int* nxt = bufB;
  for (int dstep = 1; dstep < T; dstep <<= 1) {
    for (int t = tid; t < T; t += 1024) {
      unsigned v = cur[t];
      int u = t + dstep;
      if (u < T) {
        unsigned q = cur[u];
        unsigned r = 0u;
#pragma unroll
        for (int x = 0; x < NTAG; ++x) {
          unsigned qq = (q >> (3 * x)) & 7u;
          unsigned pp = (v >> (3 * qq)) & 7u;
          r |= pp << (3 * x);
        }
        v = r;
      }
      nxt[t] = v;
    }
    __syncthreads();
    unsigned int* tmp = cur; cur = nxt; nxt = tmp;
  }

  int last = s_last;
  for (int t = tid; t < T; t += 1024) {
    out[t] = (float)((cur[t] >> (3 * last)) & 7u);
  }
}

// ---------------------------------------------------------------------------
extern "C" void kernel_launch(void* const* d_in, const int* in_sizes, int n_in,
                              void* d_out, int out_size, void* d_ws, size_t ws_size,
                              hipStream_t stream) {
  const int*   sent  = (const int*)  d_in[0];
  const float* embed = (const float*)d_in[1];
  const float* Wih_f = (const float*)d_in[2];
  const float* Whh_f = (const float*)d_in[3];
  const float* b_f   = (const float*)d_in[4];
  const float* Wih_b = (const float*)d_in[5];
  const float* Whh_b = (const float*)d_in[6];
  const float* b_b   = (const float*)d_in[7];
  const float* Wt    = (const float*)d_in[8];
  const float* bt    = (const float*)d_in[9];
  const float* trans = (const float*)d_in[10];
  const float* h0    = (const float*)d_in[11];
  const float* c0    = (const float*)d_in[12];
  int T = in_sizes[0];

  float* out = (float*)d_out;
  float* pre   = (float*)d_ws;                       // 2*T*200 floats
  float* hs    = pre + 2 * (size_t)T * G4;           // T*100
  float* feats = hs + (size_t)T * 2 * HID;           // T*5
  float* fvh   = feats + (size_t)T * NTAG;           // (T+1)*5

  k_embed_proj<<<T, 256, 0, stream>>>(sent, embed, Wih_f, b_f, Wih_b, b_b, pre, T);
  k_lstm<<<2, 256, 0, stream>>>(pre, Whh_f, Whh_b, h0, c0, hs, T);
  k_feats<<<(T * NTAG + 255) / 256, 256, 0, stream>>>(hs, Wt, bt, feats, T);
  k_viterbi<<<1, 1024, 0, stream>>>(feats, trans, fvh, out, T);
}